// Round 2
// baseline (3178.951 us; speedup 1.0000x reference)
//
#include <hip/hip_runtime.h>
#include <cstdint>
#include <cstddef>

// Problem constants
#define HN 304      // hidden size
#define G3 912      // 3*HN gate rows
#define US 76       // hidden units per slice (HN/4)
#define RS 228      // rows per slice (3*US)
#define NB 64       // batch
#define TSTEPS 1024 // encoder steps
#define LDEC 127    // decoder steps actually needed (L-1)
#define DCLS 128    // vocab / classes

// Output layout (floats): [softmax_cal 8128*128][target_cal 8128][asr_outputs 8128]
#define OUT_O1 1040384
#define OUT_O2 1048512

// Workspace layout (bytes). Proven available: ws_size >= 239,702,784.
static const size_t OFF_GI   = 0;             // 64*1024*912 f32 = 239,075,328
static const size_t OFF_HP   = 239075328ull;  // tagged h ping-pong: 2*64*304 u32
static const size_t OFF_AM   = 239230976ull;  // (spare)
static const size_t OFF_ABRT = 239233024ull;  // 256
static const size_t OFF_TAB  = 239233280ull;  // 128*912 f32
static const size_t WS_NEED  = 239700224ull;

// Dynamic-LDS layout for rnn_persist (float offsets).
//  linW staged 128x304 at stride 305 (odd stride -> conflict-free b32 reads)
//  U region unions part[4][228] (GEMV partials) and lpartd[128][9] (logit partials+logit)
#define SM_LINW   0        // 128*305 = 39040 floats
#define SM_U      39040    // 1152 floats
#define SM_HB     40192    // 304 floats (hbuf, 16B-aligned: 40192*4 % 16 == 0)
#define SM_AMXV   40496    // 4 floats
#define SM_AMXI   40500    // 4 ints
#define SM_FLOATS 40512
#define SMEM_BYTES (SM_FLOATS * 4)   // 162,048 <= 163,840 (160 KiB)

// ---------------------------------------------------------------------------
// Phase 1: gi[b,t,:] = x[b,t,:] @ enc_Wih^T + enc_bih   (unchanged)
// ---------------------------------------------------------------------------
__global__ __launch_bounds__(256) void gi_gemm(const float* __restrict__ X,
                                               const float* __restrict__ W,
                                               const float* __restrict__ bias,
                                               float* __restrict__ out)
{
    __shared__ float As[16][132];
    __shared__ float Bs[16][132];
    const int tid = threadIdx.x;
    const int m0 = blockIdx.x * 128;
    const int n0 = blockIdx.y * 128;
    const int tx = tid & 15;          // n-dir (8 cols each)
    const int ty = tid >> 4;          // m-dir (8 rows each)
    const int lr = tid >> 1;          // staging row 0..127
    const int lc = (tid & 1) * 8;     // staging k-offset 0 or 8

    float c[8][8];
#pragma unroll
    for (int i = 0; i < 8; ++i)
#pragma unroll
        for (int j = 0; j < 8; ++j) c[i][j] = 0.f;

    const bool wok = (n0 + lr < G3);
    const float* xrow = X + (size_t)(m0 + lr) * HN;
    const float* wrow = W + (size_t)(n0 + lr) * HN;
    const float4 z4 = make_float4(0.f, 0.f, 0.f, 0.f);

    float4 xa = *(const float4*)(xrow + lc);
    float4 xb = *(const float4*)(xrow + lc + 4);
    float4 wa = wok ? *(const float4*)(wrow + lc) : z4;
    float4 wb = wok ? *(const float4*)(wrow + lc + 4) : z4;

    for (int k0 = 0; k0 < HN; k0 += 16) {
        As[lc + 0][lr] = xa.x; As[lc + 1][lr] = xa.y; As[lc + 2][lr] = xa.z; As[lc + 3][lr] = xa.w;
        As[lc + 4][lr] = xb.x; As[lc + 5][lr] = xb.y; As[lc + 6][lr] = xb.z; As[lc + 7][lr] = xb.w;
        Bs[lc + 0][lr] = wa.x; Bs[lc + 1][lr] = wa.y; Bs[lc + 2][lr] = wa.z; Bs[lc + 3][lr] = wa.w;
        Bs[lc + 4][lr] = wb.x; Bs[lc + 5][lr] = wb.y; Bs[lc + 6][lr] = wb.z; Bs[lc + 7][lr] = wb.w;
        __syncthreads();
        if (k0 + 16 < HN) {
            xa = *(const float4*)(xrow + k0 + 16 + lc);
            xb = *(const float4*)(xrow + k0 + 16 + lc + 4);
            if (wok) {
                wa = *(const float4*)(wrow + k0 + 16 + lc);
                wb = *(const float4*)(wrow + k0 + 16 + lc + 4);
            }
        }
#pragma unroll
        for (int kk = 0; kk < 16; ++kk) {
            const float4 a0 = *(const float4*)&As[kk][ty * 8];
            const float4 a1 = *(const float4*)&As[kk][ty * 8 + 4];
            const float4 b0 = *(const float4*)&Bs[kk][tx * 8];
            const float4 b1 = *(const float4*)&Bs[kk][tx * 8 + 4];
            c[0][0] += a0.x * b0.x; c[0][1] += a0.x * b0.y; c[0][2] += a0.x * b0.z; c[0][3] += a0.x * b0.w;
            c[0][4] += a0.x * b1.x; c[0][5] += a0.x * b1.y; c[0][6] += a0.x * b1.z; c[0][7] += a0.x * b1.w;
            c[1][0] += a0.y * b0.x; c[1][1] += a0.y * b0.y; c[1][2] += a0.y * b0.z; c[1][3] += a0.y * b0.w;
            c[1][4] += a0.y * b1.x; c[1][5] += a0.y * b1.y; c[1][6] += a0.y * b1.z; c[1][7] += a0.y * b1.w;
            c[2][0] += a0.z * b0.x; c[2][1] += a0.z * b0.y; c[2][2] += a0.z * b0.z; c[2][3] += a0.z * b0.w;
            c[2][4] += a0.z * b1.x; c[2][5] += a0.z * b1.y; c[2][6] += a0.z * b1.z; c[2][7] += a0.z * b1.w;
            c[3][0] += a0.w * b0.x; c[3][1] += a0.w * b0.y; c[3][2] += a0.w * b0.z; c[3][3] += a0.w * b0.w;
            c[3][4] += a0.w * b1.x; c[3][5] += a0.w * b1.y; c[3][6] += a0.w * b1.z; c[3][7] += a0.w * b1.w;
            c[4][0] += a1.x * b0.x; c[4][1] += a1.x * b0.y; c[4][2] += a1.x * b0.z; c[4][3] += a1.x * b0.w;
            c[4][4] += a1.x * b1.x; c[4][5] += a1.x * b1.y; c[4][6] += a1.x * b1.z; c[4][7] += a1.x * b1.w;
            c[5][0] += a1.y * b0.x; c[5][1] += a1.y * b0.y; c[5][2] += a1.y * b0.z; c[5][3] += a1.y * b0.w;
            c[5][4] += a1.y * b1.x; c[5][5] += a1.y * b1.y; c[5][6] += a1.y * b1.z; c[5][7] += a1.y * b1.w;
            c[6][0] += a1.z * b0.x; c[6][1] += a1.z * b0.y; c[6][2] += a1.z * b0.z; c[6][3] += a1.z * b0.w;
            c[6][4] += a1.z * b1.x; c[6][5] += a1.z * b1.y; c[6][6] += a1.z * b1.z; c[6][7] += a1.z * b1.w;
            c[7][0] += a1.w * b0.x; c[7][1] += a1.w * b0.y; c[7][2] += a1.w * b0.z; c[7][3] += a1.w * b0.w;
            c[7][4] += a1.w * b1.x; c[7][5] += a1.w * b1.y; c[7][6] += a1.w * b1.z; c[7][7] += a1.w * b1.w;
        }
        __syncthreads();
    }

    const int nb = n0 + tx * 8;
    float4 bb0 = (nb + 3 < G3) ? *(const float4*)(bias + nb) : z4;
    float4 bb1 = (nb + 7 < G3) ? *(const float4*)(bias + nb + 4) : z4;
#pragma unroll
    for (int i = 0; i < 8; ++i) {
        const size_t m = (size_t)(m0 + ty * 8 + i);
        if (nb + 3 < G3) {
            float4 v = make_float4(c[i][0] + bb0.x, c[i][1] + bb0.y, c[i][2] + bb0.z, c[i][3] + bb0.w);
            *(float4*)(out + m * G3 + nb) = v;
        }
        if (nb + 7 < G3) {
            float4 v = make_float4(c[i][4] + bb1.x, c[i][5] + bb1.y, c[i][6] + bb1.z, c[i][7] + bb1.w);
            *(float4*)(out + m * G3 + nb + 4) = v;
        }
    }
}

// ---------------------------------------------------------------------------
// Phase 1b: decoder input-projection table (unchanged)
// ---------------------------------------------------------------------------
__global__ __launch_bounds__(256) void table_k(const float* __restrict__ emb,
                                               const float* __restrict__ Wih,
                                               const float* __restrict__ bih,
                                               float* __restrict__ tab)
{
    const int idx = blockIdx.x * 256 + threadIdx.x;
    const int d = idx / G3;
    const int R = idx - d * G3;
    const float4* e4 = (const float4*)(emb + (size_t)d * HN);
    const float4* w4 = (const float4*)(Wih + (size_t)R * HN);
    float acc = 0.f;
#pragma unroll
    for (int j = 0; j < 76; ++j) {
        const float4 e = e4[j], w = w4[j];
        acc += e.x * w.x; acc += e.y * w.y; acc += e.z * w.z; acc += e.w * w.w;
    }
    tab[idx] = acc + bih[R];
}

// target_cal output (unchanged)
__global__ void tcal_k(const int* __restrict__ target, float* __restrict__ out)
{
    const int i = blockIdx.x * 256 + threadIdx.x;
    if (i < NB * LDEC) {
        const int b = i / LDEC;
        const int t = i - b * LDEC;
        out[OUT_O1 + i] = (float)target[b * 128 + t + 1];
    }
}

// ---------------------------------------------------------------------------
// Sync helpers.
// barl(): LDS-only barrier. All global traffic in rnn_persist is self-ordered
// (tag polling, register-consumed loads, write-only outputs), so we do NOT
// need __syncthreads()'s vmcnt(0) drain — which was serializing the publish
// store-ack and gi loads into every step.
// Exchange: agent-scope (LLC) only — R7-identical protocol. The sc0 same-XCD
// path gave an intermittent stale read (SE-scope coherence) in R1: removed.
// ---------------------------------------------------------------------------
__device__ __forceinline__ void barl()
{
    asm volatile("s_waitcnt lgkmcnt(0)\n\ts_barrier" ::: "memory");
}

__device__ __forceinline__ void pub32(unsigned int* p, unsigned v)
{
    __hip_atomic_store(p, v, __ATOMIC_RELAXED, __HIP_MEMORY_SCOPE_AGENT);
}

// Self-tagged poll (data IS the flag) — byte-identical to the proven R7 form.
__device__ __forceinline__ unsigned poll_tag32(unsigned int* p, unsigned want, int* abortf)
{
    unsigned v; int g = 0;
    for (;;) {
        v = __hip_atomic_load(p, __ATOMIC_RELAXED, __HIP_MEMORY_SCOPE_AGENT);
        if ((v & 3u) == want) break;
        if ((++g & 255) == 0) {
            if (__hip_atomic_load(abortf, __ATOMIC_RELAXED, __HIP_MEMORY_SCOPE_AGENT) != 0) break;
            if (g > (1 << 19)) {  // deadlock valve: fail loudly, don't hang
                __hip_atomic_store(abortf, 1, __ATOMIC_RELAXED, __HIP_MEMORY_SCOPE_AGENT);
                break;
            }
        }
    }
    __asm__ volatile("" ::: "memory");
    return v;
}

// One GRU step: GEMV -> barrier -> nonlin + publish own slice + poll remote.
// Arithmetic is verbatim from the R7 kernel (bit-identical trajectory).
#define RNN_STEP(T_, GR, GZ, GN) do {                                               \
    if (comp) {                                                                     \
        const float4* hp = (const float4*)(hbuf + ksq * US);                        \
        float acc0 = 0.f, acc1 = 0.f;                                               \
        _Pragma("unroll")                                                           \
        for (int j = 0; j < 19; ++j) {                                              \
            const float4 h4 = hp[j];                                                \
            const float4 w0 = wreg0[j], w1 = wreg1[j];                              \
            acc0 += w0.x * h4.x; acc0 += w0.y * h4.y;                               \
            acc0 += w0.z * h4.z; acc0 += w0.w * h4.w;                               \
            acc1 += w1.x * h4.x; acc1 += w1.y * h4.y;                               \
            acc1 += w1.z * h4.z; acc1 += w1.w * h4.w;                               \
        }                                                                           \
        partU[ksq * RS + lp] = acc0;                                                \
        partU[ksq * RS + lp + 114] = acc1;                                          \
    }                                                                               \
    barl();                                                                         \
    if (tid < US) {                                                                 \
        const float ghr = partU[tid] + partU[RS + tid]                              \
                        + partU[2 * RS + tid] + partU[3 * RS + tid] + b_r;          \
        const float ghz = partU[US + tid] + partU[RS + US + tid]                    \
                        + partU[2 * RS + US + tid] + partU[3 * RS + US + tid] + b_z;\
        const float ghn = partU[2 * US + tid] + partU[RS + 2 * US + tid]            \
                        + partU[2 * RS + 2 * US + tid] + partU[3 * RS + 2 * US + tid] + b_n; \
        const float r_ = 1.f / (1.f + expf(-((GR) + ghr)));                         \
        const float z_ = 1.f / (1.f + expf(-((GZ) + ghz)));                         \
        const float n_ = tanhf((GN) + r_ * ghn);                                    \
        const float hnew = (1.f - z_) * n_ + z_ * hbuf[u];                          \
        const unsigned hb_ = (__float_as_uint(hnew) & ~3u) | ((unsigned)(T_) & 3u); \
        hbuf[u] = __uint_as_float(hb_);                                             \
        pub32(&hpb[((T_) & 1) * NB * HN + u], hb_);                                 \
    }                                                                               \
    if (tid < HN && cq != s) {                                                      \
        const unsigned v_ = poll_tag32(&hpb[((T_) & 1) * NB * HN + tid],            \
                                       (unsigned)(T_) & 3u, abortf);                \
        hbuf[tid] = __uint_as_float(v_);                                            \
    }                                                                               \
    barl();                                                                         \
} while (0)

// ---------------------------------------------------------------------------
// Phase 2: persistent recurrence. 256 WGs x 512 threads, 1 WG/CU (LDS forces it).
// ---------------------------------------------------------------------------
__global__ __launch_bounds__(512, 2) void rnn_persist(
    const float* __restrict__ gi,
    const float* __restrict__ encWhh, const float* __restrict__ encBhh,
    const float* __restrict__ decWhh, const float* __restrict__ decBhh,
    const float* __restrict__ tab,
    const float* __restrict__ linW, const float* __restrict__ linB,
    const int* __restrict__ target,
    unsigned int* hpk, int* abortf, float* out)
{
    const int w = blockIdx.x;
    const int b = w & 63;
    const int s = w >> 6;
    const int tid = threadIdx.x;

    extern __shared__ float smem[];
    float* linw_s = smem + SM_LINW;
    float* partU  = smem + SM_U;
    float* hbuf   = smem + SM_HB;
    float* amx_vs = smem + SM_AMXV;
    int*   amx_is = (int*)(smem + SM_AMXI);

    const bool comp = (tid < 456);
    const int ksq = tid / 114;
    const int lp  = tid - ksq * 114;
    const int g0 = lp / US,         ul0 = lp - g0 * US;
    const int g1 = (lp + 114) / US, ul1 = (lp + 114) - g1 * US;
    const int Rrow0 = g0 * HN + s * US + ul0;
    const int Rrow1 = g1 * HN + s * US + ul1;
    const int u = s * US + tid;
    const int cq = tid / US;

    unsigned int* hpb = hpk + b * HN;

    // ---- stage linW (128x304 -> stride 305) + zero h0
    for (int i = tid; i < DCLS * HN; i += 512) {
        const int r0 = i / HN;
        linw_s[r0 * 305 + (i - r0 * HN)] = linW[i];
    }
    for (int i = tid; i < HN; i += 512) hbuf[i] = 0.f;

    // ---- encoder Whh: 2 rows x 76 k per thread (152 f32 in registers)
    float4 wreg0[19], wreg1[19];
    if (comp) {
        const float4* wp0 = (const float4*)(encWhh + (size_t)Rrow0 * HN + (size_t)ksq * US);
        const float4* wp1 = (const float4*)(encWhh + (size_t)Rrow1 * HN + (size_t)ksq * US);
#pragma unroll
        for (int j = 0; j < 19; ++j) { wreg0[j] = wp0[j]; wreg1[j] = wp1[j]; }
    }
    float b_r = 0.f, b_z = 0.f, b_n = 0.f;
    if (tid < US) { b_r = encBhh[u]; b_z = encBhh[HN + u]; b_n = encBhh[2 * HN + u]; }

    __syncthreads();

    const float* gib = gi + (size_t)b * TSTEPS * G3;

    // ================= encoder: 1024 steps, unrolled x2 with gi prefetch =====
    // gi loads for step t+1 are issued before step t's GEMV; barl() does not
    // drain vmcnt, so they stay in flight across a full step.
    float grA = 0.f, gzA = 0.f, gnA = 0.f, grB = 0.f, gzB = 0.f, gnB = 0.f;
    if (tid < US) { grA = gib[u]; gzA = gib[HN + u]; gnA = gib[2 * HN + u]; }

    for (int t = 0; t < TSTEPS; t += 2) {
        if (tid < US) {
            const float* gp = gib + (size_t)(t + 1) * G3;
            grB = gp[u]; gzB = gp[HN + u]; gnB = gp[2 * HN + u];
        }
        RNN_STEP(t + 1, grA, gzA, gnA);
        if (tid < US && t + 2 < TSTEPS) {
            const float* gp = gib + (size_t)(t + 2) * G3;
            grA = gp[u]; gzA = gp[HN + u]; gnA = gp[2 * HN + u];
        }
        RNN_STEP(t + 2, grB, gzB, gnB);
    }

    // ---- decoder weights + biases
    if (comp) {
        const float4* wp0 = (const float4*)(decWhh + (size_t)Rrow0 * HN + (size_t)ksq * US);
        const float4* wp1 = (const float4*)(decWhh + (size_t)Rrow1 * HN + (size_t)ksq * US);
#pragma unroll
        for (int j = 0; j < 19; ++j) { wreg0[j] = wp0[j]; wreg1[j] = wp1[j]; }
    }
    if (tid < US) { b_r = decBhh[u]; b_z = decBhh[HN + u]; b_n = decBhh[2 * HN + u]; }
    int tok = target[b * 128];         // target[b,0,0]
    float linb_r = 0.f;
    if (tid < DCLS) linb_r = linB[tid];
    const int lr128 = tid & 127;       // logit row 0..127
    const int lq = tid >> 7;           // k-quarter 0..3 -> slices 2q,2q+1 (of 38)
    barl();

    // ================= decoder: 127 steps =================
    // All 4 slice-WGs hold bit-identical hbuf after the h exchange, so each
    // computes ALL 128 logits from LDS-resident linW and resolves argmax
    // locally -> the per-step LLC argmax exchange is gone.
    for (int t = 0; t < LDEC; ++t) {
        const int T = TSTEPS + 1 + t;
        float gr = 0.f, gz = 0.f, gn = 0.f;
        if (tid < US) {
            const float* tp = tab + (size_t)tok * G3;
            gr = tp[u]; gz = tp[HN + u]; gn = tp[2 * HN + u];
        }
        RNN_STEP(T, gr, gz, gn);

        // logits: thread (row, q) computes slices 2q and 2q+1 (19 float-pairs
        // each, same order as the R7 kernel's float2 loop).
        {
            const float* wl = linw_s + lr128 * 305 + lq * 76;
            const float* hl = hbuf + lq * 76;
            float a0 = 0.f, a1 = 0.f;
#pragma unroll
            for (int j = 0; j < 19; ++j) {
                a0 += wl[2 * j] * hl[2 * j];
                a0 += wl[2 * j + 1] * hl[2 * j + 1];
            }
#pragma unroll
            for (int j = 0; j < 19; ++j) {
                a1 += wl[38 + 2 * j] * hl[38 + 2 * j];
                a1 += wl[38 + 2 * j + 1] * hl[38 + 2 * j + 1];
            }
            partU[lr128 * 9 + 2 * lq]     = a0;
            partU[lr128 * 9 + 2 * lq + 1] = a1;
        }
        barl();
        if (tid < DCLS) {
            float lg = partU[tid * 9 + 0];
            lg += partU[tid * 9 + 1]; lg += partU[tid * 9 + 2]; lg += partU[tid * 9 + 3];
            lg += partU[tid * 9 + 4]; lg += partU[tid * 9 + 5]; lg += partU[tid * 9 + 6];
            lg += partU[tid * 9 + 7]; lg += linb_r;
            if ((tid >> 5) == s)
                out[((size_t)b * LDEC + t) * DCLS + tid] = lg;   // softmax_cal (own rows)
            partU[tid * 9 + 8] = lg;
        }
        barl();
        if (tid < 4) {                 // group argmax, ascending strict > (first-max wins)
            float bv = partU[(tid * 32) * 9 + 8]; int bi = 0;
            for (int i = 1; i < 32; ++i) {
                const float v = partU[(tid * 32 + i) * 9 + 8];
                if (v > bv) { bv = v; bi = i; }
            }
            amx_vs[tid] = bv; amx_is[tid] = tid * 32 + bi;
        }
        barl();
        {                              // identical winner on all threads, all WGs
            float gbv = amx_vs[0]; int gbi = amx_is[0];
            if (amx_vs[1] > gbv) { gbv = amx_vs[1]; gbi = amx_is[1]; }
            if (amx_vs[2] > gbv) { gbv = amx_vs[2]; gbi = amx_is[2]; }
            if (amx_vs[3] > gbv) { gbv = amx_vs[3]; gbi = amx_is[3]; }
            tok = gbi;
            if (tid == 0 && s == 0) out[OUT_O2 + (size_t)b * LDEC + t] = (float)gbi;
        }
    }
}

// ---------------------------------------------------------------------------
extern "C" void kernel_launch(void* const* d_in, const int* in_sizes, int n_in,
                              void* d_out, int out_size, void* d_ws, size_t ws_size,
                              hipStream_t stream)
{
    (void)in_sizes; (void)n_in; (void)out_size;
    const float* x      = (const float*)d_in[0];
    const int*   target = (const int*)  d_in[1];
    const float* emb    = (const float*)d_in[2];
    const float* encWih = (const float*)d_in[3];
    const float* encWhh = (const float*)d_in[4];
    const float* encBih = (const float*)d_in[5];
    const float* encBhh = (const float*)d_in[6];
    const float* decWih = (const float*)d_in[7];
    const float* decWhh = (const float*)d_in[8];
    const float* decBih = (const float*)d_in[9];
    const float* decBhh = (const float*)d_in[10];
    const float* linW   = (const float*)d_in[11];
    const float* linB   = (const float*)d_in[12];
    float* out = (float*)d_out;
    char* ws = (char*)d_ws;

    if (ws_size < WS_NEED) return;  // insufficient scratch: fail visibly

    float*        gi   = (float*)(ws + OFF_GI);
    unsigned int* hpk  = (unsigned int*)(ws + OFF_HP);
    int*          abrt = (int*)(ws + OFF_ABRT);
    float*        tab  = (float*)(ws + OFF_TAB);

    // opt-in to >64KB dynamic LDS for rnn_persist (one-time, capture-safe)
    static bool s_attr_done = false;
    if (!s_attr_done) {
        hipFuncSetAttribute(reinterpret_cast<const void*>(rnn_persist),
                            hipFuncAttributeMaxDynamicSharedMemorySize, SMEM_BYTES);
        s_attr_done = true;
    }

    // zero tagged-h ping-pong + abort flag
    hipMemsetAsync(ws + OFF_HP, 0, OFF_TAB - OFF_HP, stream);
    gi_gemm<<<dim3(512, 8), 256, 0, stream>>>(x, encWih, encBih, gi);
    table_k<<<456, 256, 0, stream>>>(emb, decWih, decBih, tab);
    tcal_k<<<32, 256, 0, stream>>>(target, out);
    rnn_persist<<<256, 512, SMEM_BYTES, stream>>>(gi, encWhh, encBhh, decWhh, decBhh, tab,
                                                  linW, linB, target, hpk, abrt, out);
}

// Round 4
// 3140.633 us; speedup vs baseline: 1.0122x; 1.0122x over previous
//
#include <hip/hip_runtime.h>
#include <cstdint>
#include <cstddef>

// Problem constants
#define HN 304      // hidden size
#define G3 912      // 3*HN gate rows
#define US 76       // hidden units per slice (HN/4)
#define RS 228      // rows per slice (3*US)
#define NB 64       // batch
#define TSTEPS 1024 // encoder steps
#define LDEC 127    // decoder steps actually needed (L-1)
#define DCLS 128    // vocab / classes

// Output layout (floats): [softmax_cal 8128*128][target_cal 8128][asr_outputs 8128]
#define OUT_O1 1040384
#define OUT_O2 1048512

// Workspace layout (bytes). Proven available: ws_size >= 239,702,784.
static const size_t OFF_GI   = 0;             // 64*1024*912 f32 = 239,075,328
static const size_t OFF_HP   = 239075328ull;  // tagged h ping-pong: 2*64*304 u32
static const size_t OFF_AM   = 239230976ull;  // (spare)
static const size_t OFF_ABRT = 239233024ull;  // 256
static const size_t OFF_TAB  = 239233280ull;  // 128*912 f32
static const size_t WS_NEED  = 239700224ull;

// Dynamic-LDS layout for rnn_persist (float offsets).
//  linW staged 128x304 at stride 306 (even -> 8B-aligned float2 rows)
//  U region unions part[4][228] (GEMV partials) and lpartd[128][9] (logit partials+logit)
#define SM_LINW   0        // 128*306 = 39168 floats
#define SM_U      39168    // 1152 floats
#define SM_HB     40320    // 304 floats (hbuf, 16B-aligned: 40320*4 % 16 == 0)
#define SM_AMXV   40624    // 4 floats
#define SM_AMXI   40628    // 4 ints
#define SM_FLOATS 40632
#define SMEM_BYTES (SM_FLOATS * 4)   // 162,528 <= 163,840 (160 KiB)

// Packed f32 FMA (VOP3P: ALL sources are 64-bit VGPR pairs).
// PKFMA_L: both result halves use src0.LO  (row 2p  broadcast)
//   low  = a.lo*b.lo + c.lo   (op_sel    [0,0,0])
//   high = a.lo*b.hi + c.hi   (op_sel_hi [0,1,1])
// PKFMA_H: both result halves use src0.HI  (row 2p+1 broadcast)
//   low  = a.hi*b.lo + c.lo   (op_sel    [1,0,0])
//   high = a.hi*b.hi + c.hi   (op_sel_hi [1,1,1])
// Each half is an independent fused FMA -> bit-identical to the scalar chain.
#define PKFMA_L(C2, A2, B2) \
    asm("v_pk_fma_f32 %0, %1, %2, %0 op_sel:[0,0,0] op_sel_hi:[0,1,1]" \
        : "+v"(C2) : "v"(A2), "v"(B2))
#define PKFMA_H(C2, A2, B2) \
    asm("v_pk_fma_f32 %0, %1, %2, %0 op_sel:[1,0,0] op_sel_hi:[1,1,1]" \
        : "+v"(C2) : "v"(A2), "v"(B2))

// ---------------------------------------------------------------------------
// Phase 1: gi[b,t,:] = x[b,t,:] @ enc_Wih^T + enc_bih   (M=65536, N=912, K=304)
// v_pk_fma_f32: 32 VOP3P/kk instead of 64 scalar FMA (halves VALU issue).
// Accumulation order per output element unchanged -> bit-identical gi.
// ---------------------------------------------------------------------------
__global__ __launch_bounds__(256) void gi_gemm(const float* __restrict__ X,
                                               const float* __restrict__ W,
                                               const float* __restrict__ bias,
                                               float* __restrict__ out)
{
    __shared__ float As[16][132];
    __shared__ float Bs[16][132];
    const int tid = threadIdx.x;
    const int m0 = blockIdx.x * 128;
    const int n0 = blockIdx.y * 128;
    const int tx = tid & 15;          // n-dir (8 cols each)
    const int ty = tid >> 4;          // m-dir (8 rows each)
    const int lr = tid >> 1;          // staging row 0..127
    const int lc = (tid & 1) * 8;     // staging k-offset 0 or 8

    float2 c2[8][4];
#pragma unroll
    for (int i = 0; i < 8; ++i)
#pragma unroll
        for (int j = 0; j < 4; ++j) { c2[i][j].x = 0.f; c2[i][j].y = 0.f; }

    const bool wok = (n0 + lr < G3);
    const float* xrow = X + (size_t)(m0 + lr) * HN;
    const float* wrow = W + (size_t)(n0 + lr) * HN;
    const float4 z4 = make_float4(0.f, 0.f, 0.f, 0.f);

    float4 xa = *(const float4*)(xrow + lc);
    float4 xb = *(const float4*)(xrow + lc + 4);
    float4 wa = wok ? *(const float4*)(wrow + lc) : z4;
    float4 wb = wok ? *(const float4*)(wrow + lc + 4) : z4;

    for (int k0 = 0; k0 < HN; k0 += 16) {
        As[lc + 0][lr] = xa.x; As[lc + 1][lr] = xa.y; As[lc + 2][lr] = xa.z; As[lc + 3][lr] = xa.w;
        As[lc + 4][lr] = xb.x; As[lc + 5][lr] = xb.y; As[lc + 6][lr] = xb.z; As[lc + 7][lr] = xb.w;
        Bs[lc + 0][lr] = wa.x; Bs[lc + 1][lr] = wa.y; Bs[lc + 2][lr] = wa.z; Bs[lc + 3][lr] = wa.w;
        Bs[lc + 4][lr] = wb.x; Bs[lc + 5][lr] = wb.y; Bs[lc + 6][lr] = wb.z; Bs[lc + 7][lr] = wb.w;
        __syncthreads();
        if (k0 + 16 < HN) {               // prefetch next K-tile during MACs
            xa = *(const float4*)(xrow + k0 + 16 + lc);
            xb = *(const float4*)(xrow + k0 + 16 + lc + 4);
            if (wok) {
                wa = *(const float4*)(wrow + k0 + 16 + lc);
                wb = *(const float4*)(wrow + k0 + 16 + lc + 4);
            }
        }
#pragma unroll
        for (int kk = 0; kk < 16; ++kk) {
            const float2* ar = (const float2*)&As[kk][ty * 8];
            const float2* br = (const float2*)&Bs[kk][tx * 8];
            float2 ap[4], bp[4];
#pragma unroll
            for (int j = 0; j < 4; ++j) { ap[j] = ar[j]; bp[j] = br[j]; }
#pragma unroll
            for (int p = 0; p < 4; ++p) {
#pragma unroll
                for (int j = 0; j < 4; ++j) {
                    PKFMA_L(c2[2 * p][j],     ap[p], bp[j]);
                    PKFMA_H(c2[2 * p + 1][j], ap[p], bp[j]);
                }
            }
        }
        __syncthreads();
    }

    // epilogue: bias + masked float4 stores (n-tiles are 16-aligned vs 912)
    const int nb = n0 + tx * 8;
    float4 bb0 = (nb + 3 < G3) ? *(const float4*)(bias + nb) : z4;
    float4 bb1 = (nb + 7 < G3) ? *(const float4*)(bias + nb + 4) : z4;
#pragma unroll
    for (int i = 0; i < 8; ++i) {
        const size_t m = (size_t)(m0 + ty * 8 + i);
        if (nb + 3 < G3) {
            float4 v = make_float4(c2[i][0].x + bb0.x, c2[i][0].y + bb0.y,
                                   c2[i][1].x + bb0.z, c2[i][1].y + bb0.w);
            *(float4*)(out + m * G3 + nb) = v;
        }
        if (nb + 7 < G3) {
            float4 v = make_float4(c2[i][2].x + bb1.x, c2[i][2].y + bb1.y,
                                   c2[i][3].x + bb1.z, c2[i][3].y + bb1.w);
            *(float4*)(out + m * G3 + nb + 4) = v;
        }
    }
}

// ---------------------------------------------------------------------------
// Phase 1b: decoder input-projection table (unchanged)
// ---------------------------------------------------------------------------
__global__ __launch_bounds__(256) void table_k(const float* __restrict__ emb,
                                               const float* __restrict__ Wih,
                                               const float* __restrict__ bih,
                                               float* __restrict__ tab)
{
    const int idx = blockIdx.x * 256 + threadIdx.x;
    const int d = idx / G3;
    const int R = idx - d * G3;
    const float4* e4 = (const float4*)(emb + (size_t)d * HN);
    const float4* w4 = (const float4*)(Wih + (size_t)R * HN);
    float acc = 0.f;
#pragma unroll
    for (int j = 0; j < 76; ++j) {
        const float4 e = e4[j], w = w4[j];
        acc += e.x * w.x; acc += e.y * w.y; acc += e.z * w.z; acc += e.w * w.w;
    }
    tab[idx] = acc + bih[R];
}

// target_cal output (unchanged)
__global__ void tcal_k(const int* __restrict__ target, float* __restrict__ out)
{
    const int i = blockIdx.x * 256 + threadIdx.x;
    if (i < NB * LDEC) {
        const int b = i / LDEC;
        const int t = i - b * LDEC;
        out[OUT_O1 + i] = (float)target[b * 128 + t + 1];
    }
}

// ---------------------------------------------------------------------------
// Sync helpers.
// barl(): LDS-only barrier (no vmcnt drain — all global traffic in rnn_persist
// is self-ordered: tag polling, register-consumed loads, write-only outputs).
// Exchange: agent-scope (LLC) only — R7-identical proven protocol.
// ---------------------------------------------------------------------------
__device__ __forceinline__ void barl()
{
    asm volatile("s_waitcnt lgkmcnt(0)\n\ts_barrier" ::: "memory");
}

__device__ __forceinline__ void pub32(unsigned int* p, unsigned v)
{
    __hip_atomic_store(p, v, __ATOMIC_RELAXED, __HIP_MEMORY_SCOPE_AGENT);
}

// Self-tagged poll (data IS the flag) — byte-identical to the proven R7 form.
__device__ __forceinline__ unsigned poll_tag32(unsigned int* p, unsigned want, int* abortf)
{
    unsigned v; int g = 0;
    for (;;) {
        v = __hip_atomic_load(p, __ATOMIC_RELAXED, __HIP_MEMORY_SCOPE_AGENT);
        if ((v & 3u) == want) break;
        if ((++g & 255) == 0) {
            if (__hip_atomic_load(abortf, __ATOMIC_RELAXED, __HIP_MEMORY_SCOPE_AGENT) != 0) break;
            if (g > (1 << 19)) {  // deadlock valve: fail loudly, don't hang
                __hip_atomic_store(abortf, 1, __ATOMIC_RELAXED, __HIP_MEMORY_SCOPE_AGENT);
                break;
            }
        }
    }
    __asm__ volatile("" ::: "memory");
    return v;
}

// One GRU step: GEMV -> barrier -> nonlin + publish own slice + poll remote.
// Arithmetic is verbatim from the R7 kernel (bit-identical trajectory).
#define RNN_STEP(T_, GR, GZ, GN) do {                                               \
    if (comp) {                                                                     \
        const float4* hp = (const float4*)(hbuf + ksq * US);                        \
        float acc0 = 0.f, acc1 = 0.f;                                               \
        _Pragma("unroll")                                                           \
        for (int j = 0; j < 19; ++j) {                                              \
            const float4 h4 = hp[j];                                                \
            const float4 w0 = wreg0[j], w1 = wreg1[j];                              \
            acc0 += w0.x * h4.x; acc0 += w0.y * h4.y;                               \
            acc0 += w0.z * h4.z; acc0 += w0.w * h4.w;                               \
            acc1 += w1.x * h4.x; acc1 += w1.y * h4.y;                               \
            acc1 += w1.z * h4.z; acc1 += w1.w * h4.w;                               \
        }                                                                           \
        partU[ksq * RS + lp] = acc0;                                                \
        partU[ksq * RS + lp + 114] = acc1;                                          \
    }                                                                               \
    barl();                                                                         \
    if (tid < US) {                                                                 \
        const float ghr = partU[tid] + partU[RS + tid]                              \
                        + partU[2 * RS + tid] + partU[3 * RS + tid] + b_r;          \
        const float ghz = partU[US + tid] + partU[RS + US + tid]                    \
                        + partU[2 * RS + US + tid] + partU[3 * RS + US + tid] + b_z;\
        const float ghn = partU[2 * US + tid] + partU[RS + 2 * US + tid]            \
                        + partU[2 * RS + 2 * US + tid] + partU[3 * RS + 2 * US + tid] + b_n; \
        const float r_ = 1.f / (1.f + expf(-((GR) + ghr)));                         \
        const float z_ = 1.f / (1.f + expf(-((GZ) + ghz)));                         \
        const float n_ = tanhf((GN) + r_ * ghn);                                    \
        const float hnew = (1.f - z_) * n_ + z_ * hbuf[u];                          \
        const unsigned hb_ = (__float_as_uint(hnew) & ~3u) | ((unsigned)(T_) & 3u); \
        hbuf[u] = __uint_as_float(hb_);                                             \
        pub32(&hpb[((T_) & 1) * NB * HN + u], hb_);                                 \
    }                                                                               \
    if (tid < HN && cq != s) {                                                      \
        const unsigned v_ = poll_tag32(&hpb[((T_) & 1) * NB * HN + tid],            \
                                       (unsigned)(T_) & 3u, abortf);                \
        hbuf[tid] = __uint_as_float(v_);                                            \
    }                                                                               \
    barl();                                                                         \
} while (0)

// ---------------------------------------------------------------------------
// Phase 2: persistent recurrence. 256 WGs x 512 threads, 1 WG/CU (LDS forces it).
// ---------------------------------------------------------------------------
__global__ __launch_bounds__(512, 2) void rnn_persist(
    const float* __restrict__ gi,
    const float* __restrict__ encWhh, const float* __restrict__ encBhh,
    const float* __restrict__ decWhh, const float* __restrict__ decBhh,
    const float* __restrict__ tab,
    const float* __restrict__ linW, const float* __restrict__ linB,
    const int* __restrict__ target,
    unsigned int* hpk, int* abortf, float* out)
{
    const int w = blockIdx.x;
    const int b = w & 63;
    const int s = w >> 6;
    const int tid = threadIdx.x;

    extern __shared__ float smem[];
    float* linw_s = smem + SM_LINW;
    float* partU  = smem + SM_U;
    float* hbuf   = smem + SM_HB;
    float* amx_vs = smem + SM_AMXV;
    int*   amx_is = (int*)(smem + SM_AMXI);

    const bool comp = (tid < 456);
    const int ksq = tid / 114;
    const int lp  = tid - ksq * 114;
    const int g0 = lp / US,         ul0 = lp - g0 * US;
    const int g1 = (lp + 114) / US, ul1 = (lp + 114) - g1 * US;
    const int Rrow0 = g0 * HN + s * US + ul0;
    const int Rrow1 = g1 * HN + s * US + ul1;
    const int u = s * US + tid;
    const int cq = tid / US;

    unsigned int* hpb = hpk + b * HN;

    // ---- stage linW (128x304 -> stride 306) + zero h0
    for (int i = tid; i < DCLS * HN; i += 512) {
        const int r0 = i / HN;
        linw_s[r0 * 306 + (i - r0 * HN)] = linW[i];
    }
    for (int i = tid; i < HN; i += 512) hbuf[i] = 0.f;

    // ---- encoder Whh: 2 rows x 76 k per thread (152 f32 in registers)
    float4 wreg0[19], wreg1[19];
    if (comp) {
        const float4* wp0 = (const float4*)(encWhh + (size_t)Rrow0 * HN + (size_t)ksq * US);
        const float4* wp1 = (const float4*)(encWhh + (size_t)Rrow1 * HN + (size_t)ksq * US);
#pragma unroll
        for (int j = 0; j < 19; ++j) { wreg0[j] = wp0[j]; wreg1[j] = wp1[j]; }
    }
    float b_r = 0.f, b_z = 0.f, b_n = 0.f;
    if (tid < US) { b_r = encBhh[u]; b_z = encBhh[HN + u]; b_n = encBhh[2 * HN + u]; }

    __syncthreads();

    const float* gib = gi + (size_t)b * TSTEPS * G3;

    // ================= encoder: 1024 steps, unrolled x2 with gi prefetch =====
    float grA = 0.f, gzA = 0.f, gnA = 0.f, grB = 0.f, gzB = 0.f, gnB = 0.f;
    if (tid < US) { grA = gib[u]; gzA = gib[HN + u]; gnA = gib[2 * HN + u]; }

    for (int t = 0; t < TSTEPS; t += 2) {
        if (tid < US) {
            const float* gp = gib + (size_t)(t + 1) * G3;
            grB = gp[u]; gzB = gp[HN + u]; gnB = gp[2 * HN + u];
        }
        RNN_STEP(t + 1, grA, gzA, gnA);
        if (tid < US && t + 2 < TSTEPS) {
            const float* gp = gib + (size_t)(t + 2) * G3;
            grA = gp[u]; gzA = gp[HN + u]; gnA = gp[2 * HN + u];
        }
        RNN_STEP(t + 2, grB, gzB, gnB);
    }

    // ---- decoder weights + biases
    if (comp) {
        const float4* wp0 = (const float4*)(decWhh + (size_t)Rrow0 * HN + (size_t)ksq * US);
        const float4* wp1 = (const float4*)(decWhh + (size_t)Rrow1 * HN + (size_t)ksq * US);
#pragma unroll
        for (int j = 0; j < 19; ++j) { wreg0[j] = wp0[j]; wreg1[j] = wp1[j]; }
    }
    if (tid < US) { b_r = decBhh[u]; b_z = decBhh[HN + u]; b_n = decBhh[2 * HN + u]; }
    int tok = target[b * 128];         // target[b,0,0]
    float linb_r = 0.f;
    if (tid < DCLS) linb_r = linB[tid];
    const int lr128 = tid & 127;       // logit row 0..127
    const int lq = tid >> 7;           // k-quarter 0..3 -> slices 2q,2q+1 (of 38)
    barl();

    // ================= decoder: 127 steps =================
    // All 4 slice-WGs hold bit-identical hbuf after the h exchange, so each
    // computes ALL 128 logits from LDS-resident linW and resolves argmax
    // locally -> no per-step LLC argmax round.  b64 reads (stride 306): 38
    // ds_read_b64/thread instead of 152 ds_read_b32 (the R2 regression).
    for (int t = 0; t < LDEC; ++t) {
        const int T = TSTEPS + 1 + t;
        float gr = 0.f, gz = 0.f, gn = 0.f;
        if (tid < US) {
            const float* tp = tab + (size_t)tok * G3;
            gr = tp[u]; gz = tp[HN + u]; gn = tp[2 * HN + u];
        }
        RNN_STEP(T, gr, gz, gn);

        // logits: thread (row, q) computes 38-elem slices 2q and 2q+1, in the
        // same ascending pair order as R7's float2 loop (bit-exact).
        {
            const float* wl = linw_s + lr128 * 306 + lq * 76;
            const float* hl = hbuf + lq * 76;
            float a0 = 0.f, a1 = 0.f;
#pragma unroll
            for (int j = 0; j < 19; ++j) {
                const float2 wv = *(const float2*)(wl + 2 * j);
                const float2 hv = *(const float2*)(hl + 2 * j);
                a0 += wv.x * hv.x; a0 += wv.y * hv.y;
            }
#pragma unroll
            for (int j = 0; j < 19; ++j) {
                const float2 wv = *(const float2*)(wl + 38 + 2 * j);
                const float2 hv = *(const float2*)(hl + 38 + 2 * j);
                a1 += wv.x * hv.x; a1 += wv.y * hv.y;
            }
            partU[lr128 * 9 + 2 * lq]     = a0;
            partU[lr128 * 9 + 2 * lq + 1] = a1;
        }
        barl();
        if (tid < DCLS) {
            float lg = partU[tid * 9 + 0];
            lg += partU[tid * 9 + 1]; lg += partU[tid * 9 + 2]; lg += partU[tid * 9 + 3];
            lg += partU[tid * 9 + 4]; lg += partU[tid * 9 + 5]; lg += partU[tid * 9 + 6];
            lg += partU[tid * 9 + 7]; lg += linb_r;
            if ((tid >> 5) == s)
                out[((size_t)b * LDEC + t) * DCLS + tid] = lg;   // softmax_cal (own rows)
            partU[tid * 9 + 8] = lg;
        }
        barl();
        if (tid < 4) {                 // group argmax, ascending strict > (first-max wins)
            float bv = partU[(tid * 32) * 9 + 8]; int bi = 0;
            for (int i = 1; i < 32; ++i) {
                const float v = partU[(tid * 32 + i) * 9 + 8];
                if (v > bv) { bv = v; bi = i; }
            }
            amx_vs[tid] = bv; amx_is[tid] = tid * 32 + bi;
        }
        barl();
        {                              // identical winner on all threads, all WGs
            float gbv = amx_vs[0]; int gbi = amx_is[0];
            if (amx_vs[1] > gbv) { gbv = amx_vs[1]; gbi = amx_is[1]; }
            if (amx_vs[2] > gbv) { gbv = amx_vs[2]; gbi = amx_is[2]; }
            if (amx_vs[3] > gbv) { gbv = amx_vs[3]; gbi = amx_is[3]; }
            tok = gbi;
            if (tid == 0 && s == 0) out[OUT_O2 + (size_t)b * LDEC + t] = (float)gbi;
        }
    }
}

// ---------------------------------------------------------------------------
extern "C" void kernel_launch(void* const* d_in, const int* in_sizes, int n_in,
                              void* d_out, int out_size, void* d_ws, size_t ws_size,
                              hipStream_t stream)
{
    (void)in_sizes; (void)n_in; (void)out_size;
    const float* x      = (const float*)d_in[0];
    const int*   target = (const int*)  d_in[1];
    const float* emb    = (const float*)d_in[2];
    const float* encWih = (const float*)d_in[3];
    const float* encWhh = (const float*)d_in[4];
    const float* encBih = (const float*)d_in[5];
    const float* encBhh = (const float*)d_in[6];
    const float* decWih = (const float*)d_in[7];
    const float* decWhh = (const float*)d_in[8];
    const float* decBih = (const float*)d_in[9];
    const float* decBhh = (const float*)d_in[10];
    const float* linW   = (const float*)d_in[11];
    const float* linB   = (const float*)d_in[12];
    float* out = (float*)d_out;
    char* ws = (char*)d_ws;

    if (ws_size < WS_NEED) return;  // insufficient scratch: fail visibly

    float*        gi   = (float*)(ws + OFF_GI);
    unsigned int* hpk  = (unsigned int*)(ws + OFF_HP);
    int*          abrt = (int*)(ws + OFF_ABRT);
    float*        tab  = (float*)(ws + OFF_TAB);

    // opt-in to >64KB dynamic LDS for rnn_persist (one-time, capture-safe)
    static bool s_attr_done = false;
    if (!s_attr_done) {
        (void)hipFuncSetAttribute(reinterpret_cast<const void*>(rnn_persist),
                                  hipFuncAttributeMaxDynamicSharedMemorySize, SMEM_BYTES);
        s_attr_done = true;
    }

    // zero tagged-h ping-pong + abort flag
    (void)hipMemsetAsync(ws + OFF_HP, 0, OFF_TAB - OFF_HP, stream);
    gi_gemm<<<dim3(512, 8), 256, 0, stream>>>(x, encWih, encBih, gi);
    table_k<<<456, 256, 0, stream>>>(emb, decWih, decBih, tab);
    tcal_k<<<32, 256, 0, stream>>>(target, out);
    rnn_persist<<<256, 512, SMEM_BYTES, stream>>>(gi, encWhh, encBhh, decWhh, decBhh, tab,
                                                  linW, linB, target, hpk, abrt, out);
}